// Round 3
// baseline (608.287 us; speedup 1.0000x reference)
//
#include <hip/hip_runtime.h>

// Sizes
#define Gg   128
#define N1   512
#define FH   128
#define K1   256
#define K2   128

typedef __bf16 bf16x8 __attribute__((ext_vector_type(8)));
typedef float  floatx4 __attribute__((ext_vector_type(4)));

__device__ inline float wredsum(float v) {
#pragma unroll
    for (int o = 32; o; o >>= 1) v += __shfl_xor(v, o, 64);
    return v;
}
__device__ inline float wredmax(float v) {
#pragma unroll
    for (int o = 32; o; o >>= 1) v = fmaxf(v, __shfl_xor(v, o, 64));
    return v;
}
__device__ inline unsigned short bf_rne(float x) {
    unsigned u = __float_as_uint(x);
    return (unsigned short)((u + 0x7fffu + ((u >> 16) & 1u)) >> 16);
}
// async global->LDS, 16B per lane; LDS dest wave-uniform base (HW adds lane*16),
// global src per-lane (pre-swizzle there for swizzled LDS content)
__device__ __forceinline__ void gll16(const void* gsrc, void* lds) {
    __builtin_amdgcn_global_load_lds(
        (const __attribute__((address_space(1))) unsigned int*)gsrc,
        (__attribute__((address_space(3))) unsigned int*)lds, 16, 0, 0);
}

// ---------------------------------------------------------------------------
// degrees from adj (row sums; adj values exactly 0/1) + bf16 copy of adj
// (truncation is exact for 0/1); adjbf feeds k_aggmm's A-DMA path
// ---------------------------------------------------------------------------
__global__ __launch_bounds__(256) void k_prep(const float* __restrict__ adj,
        unsigned short* __restrict__ adjbf,
        float* __restrict__ dinv_gcn, float* __restrict__ dinv_info) {
    int wave = threadIdx.x >> 6, lane = threadIdx.x & 63;
    long long row = (long long)blockIdx.x * 4 + wave;
    const float* ar = adj + row * N1;
    float s = 0.f;
    unsigned short ub[8] __attribute__((aligned(16)));
#pragma unroll
    for (int c = 0; c < 2; ++c) {
        float4 v = *(const float4*)(ar + lane * 8 + c * 4);
        s += (v.x + v.y) + (v.z + v.w);
        ub[c * 4 + 0] = (unsigned short)(__float_as_uint(v.x) >> 16);
        ub[c * 4 + 1] = (unsigned short)(__float_as_uint(v.y) >> 16);
        ub[c * 4 + 2] = (unsigned short)(__float_as_uint(v.z) >> 16);
        ub[c * 4 + 3] = (unsigned short)(__float_as_uint(v.w) >> 16);
    }
    *(uint4*)(adjbf + row * N1 + lane * 8) = *(const uint4*)ub;
    s = wredsum(s);
    if (lane == 0) {
        dinv_gcn[row]  = rsqrtf(s + 1.0f);
        dinv_info[row] = 1.0f / fmaxf(s, 1.0f);
    }
}

// ---------------------------------------------------------------------------
// transpose + 3-way bf16 split: feat[g*512][128] fp32 -> T{hi,mid,lo}
// Layout: k-step-blocked T[g][ks][f][32] (ks = node>>5), 16B chunks XOR-swizzled:
// content chunk c of row f stored at position c ^ ((f>>1)&3)  (bank-conflict fix,
// read side in k_aggmm applies the same XOR; global_load_lds stays linear)
// ---------------------------------------------------------------------------
__global__ __launch_bounds__(256) void k_tsplit(const float* __restrict__ feat,
        unsigned short* __restrict__ Thi, unsigned short* __restrict__ Tmid,
        unsigned short* __restrict__ Tlo) {
    __shared__ float tile[64 * 65];
    int b = blockIdx.x;                    // G * 8 * 2
    int g = b >> 4, rb = (b >> 1) & 7, cb = b & 1;
    int t = threadIdx.x;
    {
        int r0 = t >> 4, c4 = t & 15;
#pragma unroll
        for (int i = 0; i < 4; ++i) {
            int r = r0 + i * 16;
            float4 v = *(const float4*)(feat + ((long long)g * 512 + rb * 64 + r) * 128 + cb * 64 + c4 * 4);
            tile[r * 65 + c4 * 4 + 0] = v.x;
            tile[r * 65 + c4 * 4 + 1] = v.y;
            tile[r * 65 + c4 * 4 + 2] = v.z;
            tile[r * 65 + c4 * 4 + 3] = v.w;
        }
    }
    __syncthreads();
    int tf = t >> 2, chunk = t & 3;
    unsigned short hbuf[16] __attribute__((aligned(16)));
    unsigned short mbuf[16] __attribute__((aligned(16)));
    unsigned short lbuf[16] __attribute__((aligned(16)));
#pragma unroll
    for (int i = 0; i < 16; ++i) {
        int m = chunk * 16 + i;
        float v = tile[m * 65 + tf];
        unsigned short h = bf_rne(v);
        float fh = __uint_as_float((unsigned)h << 16);
        float r1 = v - fh;
        unsigned short md = bf_rne(r1);
        float fm = __uint_as_float((unsigned)md << 16);
        float r2 = r1 - fm;
        unsigned short lo = bf_rne(r2);
        hbuf[i] = h; mbuf[i] = md; lbuf[i] = lo;
    }
    // node n = rb*64 + chunk*16 + i ; ks = rb*2 + (chunk>>1) ; within-window chunk
    // c0 = (chunk&1)*2 (+1 for i>=8); swizzle s = (f>>1)&3
    int sxz = (tf >> 1) & 3;               // f = cb*64+tf, cb*64 = 0 mod 128
    int c0 = (chunk & 1) * 2;
    int p0 = (c0 ^ sxz) * 8, p1 = ((c0 + 1) ^ sxz) * 8;
    long long obase = (long long)g * 65536 + (rb * 2 + (chunk >> 1)) * 4096
                    + (cb * 64 + tf) * 32;
    *(uint4*)(Thi + obase + p0)  = *(const uint4*)&hbuf[0];
    *(uint4*)(Thi + obase + p1)  = *(const uint4*)&hbuf[8];
    *(uint4*)(Tmid + obase + p0) = *(const uint4*)&mbuf[0];
    *(uint4*)(Tmid + obase + p1) = *(const uint4*)&mbuf[8];
    *(uint4*)(Tlo + obase + p0)  = *(const uint4*)&lbuf[0];
    *(uint4*)(Tlo + obase + p1)  = *(const uint4*)&lbuf[8];
}

// ---------------------------------------------------------------------------
// MFMA aggregation: C = adj(512x512, exact bf16) @ (Bhi+Bmid+Blo)(512x128)
//  EPI 0 (gcn):  outH[m][n] = relu(di[m]*(C+hx[m][n]) + bias[n])   (in-place over hx ok)
//  EPI 1 (info): outS[m]    = sum_n |hx[m][n] - C*di[m]|
// Block: 128 rows x 128 cols, 4 waves (2x2 of 64x64), mfma_f32_16x16x32_bf16.
// T3 minimal 2-phase pipeline: double-buffered LDS, next k-step's 8 DMA issued
// BEFORE compute, counted s_waitcnt vmcnt(8) (never 0 in main loop) + raw
// s_barrier. XOR chunk-swizzle on both A (via global addr) and B (via k_tsplit).
// ---------------------------------------------------------------------------
template<int EPI>
__global__ __launch_bounds__(256) void k_aggmm(const unsigned short* __restrict__ adjbf,
        const unsigned short* __restrict__ Bhi, const unsigned short* __restrict__ Bmid,
        const unsigned short* __restrict__ Blo,
        const float* __restrict__ dvec, const float* __restrict__ hx,
        const float* __restrict__ bias, float* __restrict__ outH, float* __restrict__ outS) {
    __shared__ unsigned short Al[2][4096];            // 2 x 8KB linear A tile
    __shared__ unsigned short Blin[2][3][4096];       // 2 x 24KB B tiles
    __shared__ float sred[2][128];
    int b = blockIdx.x;                               // 512 blocks
    int g  = (b & 7) + ((b >> 5) << 3);               // XCD swizzle: 4 row-blocks of g share an XCD
    int rb = (b >> 3) & 3;
    int tid = threadIdx.x;
    int w = tid >> 6, lane = tid & 63;
    int wm = w >> 1, wn = w & 1;
    int ln = lane & 15, quad = lane >> 4;
    int aoff = ((quad ^ ((lane >> 1) & 3)) << 4);     // read-side XOR de-swizzle (bytes)
    floatx4 acc[4][4];
#pragma unroll
    for (int i = 0; i < 4; ++i)
#pragma unroll
        for (int j = 0; j < 4; ++j) { floatx4 z = {0.f, 0.f, 0.f, 0.f}; acc[i][j] = z; }

    const char* bsrc0 = (const char*)(Bhi  + (long long)g * 65536);
    const char* bsrc1 = (const char*)(Bmid + (long long)g * 65536);
    const char* bsrc2 = (const char*)(Blo  + (long long)g * 65536);
    // A per-lane pre-swizzled global source (rows w*32..w*32+31 per wave)
    int r1 = w * 32 + (lane >> 2);
    int c1 = (lane & 3) ^ ((r1 >> 1) & 3);
    int r2 = r1 + 16;
    int c2 = (lane & 3) ^ ((r2 >> 1) & 3);
    const unsigned short* abase = adjbf + ((long long)g * 512 + rb * 128) * 512;
    const unsigned short* asrc1 = abase + (long long)r1 * 512 + c1 * 8;
    const unsigned short* asrc2 = abase + (long long)r2 * 512 + c2 * 8;

    // stage k-block (kk) into buffer bi: 8 gll16 per wave (2 A + 6 B)
#define STAGE(bi, kkv) do {                                                   \
        char* aldst = (char*)&Al[bi][0] + w * 2048;                           \
        gll16(asrc1 + (kkv), aldst);                                          \
        gll16(asrc2 + (kkv), aldst + 1024);                                   \
        long long soff = (long long)((kkv) >> 5) * 8192 + (w * 2048) + (lane << 4); \
        char* l0 = (char*)&Blin[bi][0][0] + w * 2048;                         \
        char* l1 = (char*)&Blin[bi][1][0] + w * 2048;                         \
        char* l2 = (char*)&Blin[bi][2][0] + w * 2048;                         \
        gll16(bsrc0 + soff,        l0);                                       \
        gll16(bsrc0 + soff + 1024, l0 + 1024);                                \
        gll16(bsrc1 + soff,        l1);                                       \
        gll16(bsrc1 + soff + 1024, l1 + 1024);                                \
        gll16(bsrc2 + soff,        l2);                                       \
        gll16(bsrc2 + soff + 1024, l2 + 1024);                                \
    } while (0)

    STAGE(0, 0);                                      // prologue prefetch
    for (int kk = 0; kk < 512; kk += 32) {
        int cur = (kk >> 5) & 1;
        if (kk + 32 < 512) {
            STAGE(cur ^ 1, kk + 32);                  // prefetch next k-block
            asm volatile("s_waitcnt vmcnt(8)" ::: "memory");   // old stage done, new in flight
        } else {
            asm volatile("s_waitcnt vmcnt(0)" ::: "memory");   // epilogue drain
        }
        __builtin_amdgcn_sched_barrier(0);
        __builtin_amdgcn_s_barrier();                 // all waves: buf[cur] ready
        bf16x8 af[4];
#pragma unroll
        for (int tm = 0; tm < 4; ++tm)
            af[tm] = *(const bf16x8*)((const char*)&Al[cur][0] + (wm * 64 + tm * 16 + ln) * 64 + aoff);
#pragma unroll
        for (int s = 0; s < 3; ++s) {
#pragma unroll
            for (int tn = 0; tn < 4; ++tn) {
                bf16x8 bfr = *(const bf16x8*)((const char*)&Blin[cur][s][0]
                                              + (wn * 64 + tn * 16 + ln) * 64 + aoff);
#pragma unroll
                for (int tm = 0; tm < 4; ++tm)
                    acc[tm][tn] = __builtin_amdgcn_mfma_f32_16x16x32_bf16(af[tm], bfr, acc[tm][tn], 0, 0, 0);
            }
        }
        __builtin_amdgcn_sched_barrier(0);
        __builtin_amdgcn_s_barrier();                 // buf[cur] free for overwrite next iter
    }
#undef STAGE
    long long rowbase = (long long)g * 512 + rb * 128;
    if (EPI == 0) {
#pragma unroll
        for (int tm = 0; tm < 4; ++tm)
#pragma unroll
        for (int r = 0; r < 4; ++r) {
            int ml = wm * 64 + tm * 16 + quad * 4 + r;
            long long grow = rowbase + ml;
            float di = dvec[grow];
#pragma unroll
            for (int tn = 0; tn < 4; ++tn) {
                int nc = wn * 64 + tn * 16 + ln;
                float hv = hx[grow * 128 + nc];
                float o = fmaxf(fmaf(di, acc[tm][tn][r] + hv, bias[nc]), 0.f);
                outH[grow * 128 + nc] = o;
            }
        }
    } else {
#pragma unroll
        for (int tm = 0; tm < 4; ++tm)
#pragma unroll
        for (int r = 0; r < 4; ++r) {
            int ml = wm * 64 + tm * 16 + quad * 4 + r;
            long long grow = rowbase + ml;
            float di = dvec[grow];
            float v = 0.f;
#pragma unroll
            for (int tn = 0; tn < 4; ++tn) {
                int nc = wn * 64 + tn * 16 + ln;
                float hv = hx[grow * 128 + nc];
                v += fabsf(hv - acc[tm][tn][r] * di);
            }
            v += __shfl_xor(v, 1); v += __shfl_xor(v, 2);
            v += __shfl_xor(v, 4); v += __shfl_xor(v, 8);
            if (ln == 0) sred[wn][ml] = v;
        }
        __syncthreads();
        if (tid < 128) outS[rowbase + tid] = sred[0][tid] + sred[1][tid];
    }
}

// ---------------------------------------------------------------------------
// Row-weight GEMM: C[M,128] = rs[row] * (A[M,128] @ W[128,128])  (rs optional)
// ---------------------------------------------------------------------------
__global__ __launch_bounds__(256) void k_gemm_rw(const float* __restrict__ A,
        const float* __restrict__ W, float* __restrict__ C,
        const float* __restrict__ rs) {
    __shared__ float Al[64][68];
    __shared__ float Wl[64][132];
    long long row0 = (long long)blockIdx.x * 64;
    int tid = threadIdx.x, tr = tid >> 4, tc = tid & 15;
    float acc[4][8] = {};
    for (int ch = 0; ch < 2; ++ch) {
        for (int p = tid; p < 1024; p += 256) {
            int r = p >> 4, c4 = p & 15;
            *(float4*)&Al[r][c4 * 4] = *(const float4*)(A + (row0 + r) * 128 + ch * 64 + c4 * 4);
        }
        for (int p = tid; p < 2048; p += 256) {
            int r = p >> 5, c4 = p & 31;
            *(float4*)&Wl[r][c4 * 4] = *(const float4*)(W + (ch * 64 + r) * 128 + c4 * 4);
        }
        __syncthreads();
        for (int k = 0; k < 64; ++k) {
            float4 w0 = *(const float4*)&Wl[k][tc * 8];
            float4 w1 = *(const float4*)&Wl[k][tc * 8 + 4];
            float w[8] = {w0.x, w0.y, w0.z, w0.w, w1.x, w1.y, w1.z, w1.w};
#pragma unroll
            for (int i = 0; i < 4; ++i) {
                float a = Al[tr * 4 + i][k];
#pragma unroll
                for (int j = 0; j < 8; ++j) acc[i][j] = fmaf(a, w[j], acc[i][j]);
            }
        }
        __syncthreads();
    }
#pragma unroll
    for (int i = 0; i < 4; ++i) {
        long long r = row0 + tr * 4 + i;
        float sc = rs ? rs[r] : 1.0f;
        *(float4*)(C + r * 128 + tc * 8)     = make_float4(sc * acc[i][0], sc * acc[i][1], sc * acc[i][2], sc * acc[i][3]);
        *(float4*)(C + r * 128 + tc * 8 + 4) = make_float4(sc * acc[i][4], sc * acc[i][5], sc * acc[i][6], sc * acc[i][7]);
    }
}

// ---------------------------------------------------------------------------
// top-k: bitonic sort of packed keys (~ord(val) << 32 | idx) ascending
//  => value descending, index ascending tiebreak (matches jax.lax.top_k)
// ---------------------------------------------------------------------------
template<int NT, int KSEL>
__global__ __launch_bounds__(256) void k_topk(const float* __restrict__ s, int* __restrict__ idx) {
    __shared__ unsigned long long keys[NT];
    int g = blockIdx.x;
    const float* sg = s + g * NT;
    for (int t = threadIdx.x; t < NT; t += 256) {
        unsigned int b = __float_as_uint(sg[t]);
        unsigned int ord = (b & 0x80000000u) ? ~b : (b | 0x80000000u);
        keys[t] = ((unsigned long long)(~ord) << 32) | (unsigned int)t;
    }
    __syncthreads();
    for (int k = 2; k <= NT; k <<= 1) {
        for (int j = k >> 1; j > 0; j >>= 1) {
            for (int i = threadIdx.x; i < NT; i += 256) {
                int l = i ^ j;
                if (l > i) {
                    bool dir = ((i & k) == 0);
                    unsigned long long a = keys[i], b2 = keys[l];
                    bool sw = dir ? (a > b2) : (a < b2);
                    if (sw) { keys[i] = b2; keys[l] = a; }
                }
            }
            __syncthreads();
        }
    }
    for (int t = threadIdx.x; t < KSEL; t += 256)
        idx[g * KSEL + t] = (int)(keys[t] & 0xffffffffu);
}

// ---------------------------------------------------------------------------
// gather pooled rows + attention dot products
// ---------------------------------------------------------------------------
template<int KK>
__global__ __launch_bounds__(256) void k_gather(const float* __restrict__ h, int srcN,
        const int* __restrict__ idx, const float* __restrict__ atts, const float* __restrict__ attd,
        float* __restrict__ xk, float* __restrict__ as_, float* __restrict__ ad_) {
    int wave = threadIdx.x >> 6, lane = threadIdx.x & 63;
    int r = blockIdx.x * 4 + wave;          // < G*KK
    int g = r / KK;
    int j = idx[r];
    float2 v = *(const float2*)(h + ((long long)g * srcN + j) * 128 + lane * 2);
    *(float2*)(xk + (long long)r * 128 + lane * 2) = v;
    float2 sv = *(const float2*)(atts + lane * 2);
    float2 dv = *(const float2*)(attd + lane * 2);
    float ps = v.x * sv.x + v.y * sv.y;
    float pd = v.x * dv.x + v.y * dv.y;
    ps = wredsum(ps); pd = wredsum(pd);
    if (lane == 0) { as_[r] = ps; ad_[r] = pd; }
}

// ---------------------------------------------------------------------------
// attention: attn = softmax(leaky(as_i + ad_j) + adjSrc[idx_i,idx_j]) + deg epilogue
// ---------------------------------------------------------------------------
template<int KK, int SRCN>
__global__ __launch_bounds__(256) void k_attn(const float* __restrict__ adjSrc,
        const int* __restrict__ idx, const float* __restrict__ as_, const float* __restrict__ ad_,
        float* __restrict__ attn, float* __restrict__ dgo, float* __restrict__ dio) {
    constexpr int E = KK / 64;
    __shared__ int   idxL[KK];
    __shared__ float adL[KK];
    __shared__ float rowL[4][SRCN];
    int bpg = KK / 4;
    int g = blockIdx.x / bpg;
    int wave = threadIdx.x >> 6, lane = threadIdx.x & 63;
    int i = (blockIdx.x % bpg) * 4 + wave;
    for (int t = threadIdx.x; t < KK; t += 256) { idxL[t] = idx[g * KK + t]; adL[t] = ad_[g * KK + t]; }
    __syncthreads();
    int ri = idxL[i];
    const float* arow = adjSrc + ((long long)g * SRCN + ri) * SRCN;
    for (int c = lane; c < SRCN; c += 64) rowL[wave][c] = arow[c];
    float asi = as_[g * KK + i];
    float vals[E];
    float m = -1e30f;
#pragma unroll
    for (int e = 0; e < E; ++e) {
        int j = e * 64 + lane;
        float x = asi + adL[j];
        x = (x >= 0.f) ? x : 0.2f * x;
        x += rowL[wave][idxL[j]];       // LAMB = 1.0
        vals[e] = x; m = fmaxf(m, x);
    }
    m = wredmax(m);
    float S = 0.f;
#pragma unroll
    for (int e = 0; e < E; ++e) { vals[e] = expf(vals[e] - m); S += vals[e]; }
    S = wredsum(S);
    float inv = 1.f / S, rs = 0.f;
    float* orow = attn + ((long long)g * KK + i) * KK;
#pragma unroll
    for (int e = 0; e < E; ++e) { float p = vals[e] * inv; rs += p; orow[e * 64 + lane] = p; }
    rs = wredsum(rs);
    if (lane == 0) { dgo[g * KK + i] = rsqrtf(rs + 1.f); dio[g * KK + i] = 1.f / fmaxf(rs, 1.f); }
}

// ---------------------------------------------------------------------------
// readout: [max over rows, mean over rows] -> (G, 256)
// ---------------------------------------------------------------------------
template<int KK>
__global__ __launch_bounds__(128) void k_readout(const float* __restrict__ xk, float* __restrict__ xo) {
    int g = blockIdx.x, f = threadIdx.x;
    const float* p = xk + (long long)g * KK * 128 + f;
    float m = -1e30f, s = 0.f;
    for (int r = 0; r < KK; ++r) { float v = p[r * 128]; m = fmaxf(m, v); s += v; }
    xo[g * 256 + f] = m;
    xo[g * 256 + 128 + f] = s * (1.0f / KK);
}

// ---------------------------------------------------------------------------
// dense batched agg GEMM: C = A(KKxKK) @ [opt dinv_j *] Y(KKx128)
//  EPI 0: outH = relu(di*C + di^2*hx + bias)   EPI 1: outS_i = sum_f |hx - C*di|
// ---------------------------------------------------------------------------
template<int KK, bool SCALEY, int EPI>
__global__ __launch_bounds__(256) void k_agg(const float* __restrict__ A, const float* __restrict__ Y,
        const float* __restrict__ dg, const float* __restrict__ di_,
        const float* __restrict__ bias, const float* __restrict__ hx,
        float* __restrict__ outH, float* __restrict__ outS) {
    __shared__ float Al[64][68];
    __shared__ float Yl[64][132];
    __shared__ float red[64][17];
    constexpr int RB = KK / 64;
    int g = blockIdx.x / RB;
    int rb = blockIdx.x % RB;
    const float* Ag = A + (long long)g * KK * KK;
    const float* Yg = Y + (long long)g * KK * 128;
    int tid = threadIdx.x, tr = tid >> 4, tc = tid & 15;
    float acc[4][8] = {};
    for (int ch = 0; ch < KK / 64; ++ch) {
        for (int p = tid; p < 1024; p += 256) {
            int r = p >> 4, c4 = p & 15;
            *(float4*)&Al[r][c4 * 4] = *(const float4*)(Ag + (rb * 64 + r) * KK + ch * 64 + c4 * 4);
        }
        for (int p = tid; p < 2048; p += 256) {
            int r = p >> 5, c4 = p & 31;
            float4 v = *(const float4*)(Yg + (ch * 64 + r) * 128 + c4 * 4);
            if (SCALEY) { float sc = dg[g * KK + ch * 64 + r]; v.x *= sc; v.y *= sc; v.z *= sc; v.w *= sc; }
            *(float4*)&Yl[r][c4 * 4] = v;
        }
        __syncthreads();
        for (int k = 0; k < 64; ++k) {
            float4 w0 = *(const float4*)&Yl[k][tc * 8];
            float4 w1 = *(const float4*)&Yl[k][tc * 8 + 4];
            float w[8] = {w0.x, w0.y, w0.z, w0.w, w1.x, w1.y, w1.z, w1.w};
#pragma unroll
            for (int i = 0; i < 4; ++i) {
                float a = Al[tr * 4 + i][k];
#pragma unroll
                for (int j = 0; j < 8; ++j) acc[i][j] = fmaf(a, w[j], acc[i][j]);
            }
        }
        __syncthreads();
    }
    int i0 = rb * 64 + tr * 4;
    if (EPI == 0) {
#pragma unroll
        for (int i = 0; i < 4; ++i) {
            long long gi = (long long)g * KK + i0 + i;
            float d = dg[gi], dd = d * d;
            float4 x0 = *(const float4*)(hx + gi * 128 + tc * 8);
            float4 x1 = *(const float4*)(hx + gi * 128 + tc * 8 + 4);
            float4 b0 = *(const float4*)(bias + tc * 8);
            float4 b1 = *(const float4*)(bias + tc * 8 + 4);
            float4 o0, o1;
            o0.x = fmaxf(fmaf(d, acc[i][0], fmaf(dd, x0.x, b0.x)), 0.f);
            o0.y = fmaxf(fmaf(d, acc[i][1], fmaf(dd, x0.y, b0.y)), 0.f);
            o0.z = fmaxf(fmaf(d, acc[i][2], fmaf(dd, x0.z, b0.z)), 0.f);
            o0.w = fmaxf(fmaf(d, acc[i][3], fmaf(dd, x0.w, b0.w)), 0.f);
            o1.x = fmaxf(fmaf(d, acc[i][4], fmaf(dd, x1.x, b1.x)), 0.f);
            o1.y = fmaxf(fmaf(d, acc[i][5], fmaf(dd, x1.y, b1.y)), 0.f);
            o1.z = fmaxf(fmaf(d, acc[i][6], fmaf(dd, x1.z, b1.z)), 0.f);
            o1.w = fmaxf(fmaf(d, acc[i][7], fmaf(dd, x1.w, b1.w)), 0.f);
            *(float4*)(outH + gi * 128 + tc * 8)     = o0;
            *(float4*)(outH + gi * 128 + tc * 8 + 4) = o1;
        }
    } else {
#pragma unroll
        for (int i = 0; i < 4; ++i) {
            long long gi = (long long)g * KK + i0 + i;
            float d = di_[gi];
            float4 x0 = *(const float4*)(hx + gi * 128 + tc * 8);
            float4 x1 = *(const float4*)(hx + gi * 128 + tc * 8 + 4);
            float p = fabsf(x0.x - acc[i][0] * d) + fabsf(x0.y - acc[i][1] * d)
                    + fabsf(x0.z - acc[i][2] * d) + fabsf(x0.w - acc[i][3] * d)
                    + fabsf(x1.x - acc[i][4] * d) + fabsf(x1.y - acc[i][5] * d)
                    + fabsf(x1.z - acc[i][6] * d) + fabsf(x1.w - acc[i][7] * d);
            red[tr * 4 + i][tc] = p;
        }
        __syncthreads();
        if (tid < 64) {
            float s = 0.f;
#pragma unroll
            for (int t = 0; t < 16; ++t) s += red[tid][t];
            outS[(long long)g * KK + rb * 64 + tid] = s;
        }
    }
}

// ---------------------------------------------------------------------------
// final MLP + softmax, one block per graph
// ---------------------------------------------------------------------------
__global__ __launch_bounds__(128) void k_mlp(const float* __restrict__ x1, const float* __restrict__ x2,
        const float* __restrict__ x3,
        const float* __restrict__ Wl1, const float* __restrict__ bl1,
        const float* __restrict__ Wl2, const float* __restrict__ bl2,
        const float* __restrict__ Wl3, const float* __restrict__ bl3,
        float* __restrict__ out) {
    __shared__ float z[256], z1[128], z2[64], lg[10];
    int g = blockIdx.x, t = threadIdx.x;
    for (int k = t; k < 256; k += 128)
        z[k] = fmaxf(x1[g * 256 + k], 0.f) + fmaxf(x2[g * 256 + k], 0.f) + fmaxf(x3[g * 256 + k], 0.f);
    __syncthreads();
    {
        float acc = bl1[t];
        for (int k = 0; k < 256; ++k) acc = fmaf(z[k], Wl1[k * 128 + t], acc);
        z1[t] = fmaxf(acc, 0.f);
    }
    __syncthreads();
    if (t < 64) {
        float acc = bl2[t];
        for (int k = 0; k < 128; ++k) acc = fmaf(z1[k], Wl2[k * 64 + t], acc);
        z2[t] = fmaxf(acc, 0.f);
    }
    __syncthreads();
    if (t < 10) {
        float acc = bl3[t];
        for (int k = 0; k < 64; ++k) acc = fmaf(z2[k], Wl3[k * 10 + t], acc);
        lg[t] = acc;
    }
    __syncthreads();
    if (t == 0) {
        float m = -1e30f;
        for (int c = 0; c < 10; ++c) m = fmaxf(m, lg[c]);
        float S = 0.f;
        float e[10];
        for (int c = 0; c < 10; ++c) { e[c] = expf(lg[c] - m); S += e[c]; }
        float inv = 1.f / S;
        for (int c = 0; c < 10; ++c) out[g * 10 + c] = e[c] * inv;
    }
}

// ---------------------------------------------------------------------------
extern "C" void kernel_launch(void* const* d_in, const int* in_sizes, int n_in,
                              void* d_out, int out_size, void* d_ws, size_t ws_size,
                              hipStream_t stream) {
    const float* x     = (const float*)d_in[0];
    const float* adj   = (const float*)d_in[1];
    const float* W1    = (const float*)d_in[2];
    const float* b1    = (const float*)d_in[3];
    const float* W2    = (const float*)d_in[4];
    const float* b2    = (const float*)d_in[5];
    const float* W3    = (const float*)d_in[6];
    const float* b3    = (const float*)d_in[7];
    const float* att1s = (const float*)d_in[8];
    const float* att1d = (const float*)d_in[9];
    const float* att2s = (const float*)d_in[10];
    const float* att2d = (const float*)d_in[11];
    const float* Wl1   = (const float*)d_in[12];
    const float* bl1   = (const float*)d_in[13];
    const float* Wl2   = (const float*)d_in[14];
    const float* bl2   = (const float*)d_in[15];
    const float* Wl3   = (const float*)d_in[16];
    const float* bl3   = (const float*)d_in[17];
    float* out = (float*)d_out;

    char* ws = (char*)d_ws;
    // --- workspace layout (lifetimes annotated; harness ws >= 512MB) ---
    // T region [0 .. 50,331,648): dxw1T/h1T hi|mid|lo; later xk1/xw2/h2; later xw3/h3/xk2/a2
    unsigned short* Thi  = (unsigned short*)(ws + 0);
    unsigned short* Tmid = (unsigned short*)(ws + 16777216);
    unsigned short* Tlo  = (unsigned short*)(ws + 33554432);
    float* xk1 = (float*)(ws + 0);            // after info1 done
    float* xw2 = (float*)(ws + 16777216);
    float* h2  = (float*)(ws + 33554432);
    float* xk2 = (float*)(ws + 16777216);     // xw2 slot (dead after agg2-epi0)
    float* a2  = (float*)(ws + 25165824);
    float* xw3 = (float*)(ws + 0);            // xk1 slot (dead after readout1)
    float* h3  = (float*)(ws + 8388608);
    // A region [50,331,648 .. 83,886,080): dxw1 -> h1 (in-place) -> a1
    float* dxw1 = (float*)(ws + 50331648);
    float* h1   = dxw1;                       // pointwise in-place epilogue
    float* a1   = dxw1;                       // after h1 dead (post-gather1)
    // smalls
    float* s1      = (float*)(ws + 83886080);
    int*   idx1    = (int*)  (ws + 84148224);
    float* as1     = (float*)(ws + 84279296);
    float* ad1     = (float*)(ws + 84410368);
    float* dinv_g1 = (float*)(ws + 84541440);
    float* dinv_i1 = (float*)(ws + 84803584);
    float* dinv_g2 = (float*)(ws + 85065728);
    float* dinv_i2 = (float*)(ws + 85196800);
    float* x1r     = (float*)(ws + 85327872);
    float* s2      = (float*)(ws + 85458944);
    int*   idx2    = (int*)  (ws + 85590016);
    float* as2     = (float*)(ws + 85655552);
    float* ad2     = (float*)(ws + 85721088);
    float* dinv_g3 = (float*)(ws + 85786624);
    float* dinv_i3 = (float*)(ws + 85852160);
    float* x2r     = (float*)(ws + 85917696);
    float* x3r     = (float*)(ws + 86048768);
    // adjbf (bf16 adjacency) [96MB .. 160MB): lives k_prep -> aggmm<1>
    unsigned short* adjbf = (unsigned short*)(ws + 100663296);

    // stage 1: full graph (N=512), adjacency aggregations via bf16-split MFMA
    k_prep<<<Gg * N1 / 4, 256, 0, stream>>>(adj, adjbf, dinv_g1, dinv_i1);
    k_gemm_rw<<<Gg * N1 / 64, 256, 0, stream>>>(x, W1, dxw1, dinv_g1);
    k_tsplit<<<Gg * 16, 256, 0, stream>>>(dxw1, Thi, Tmid, Tlo);
    k_aggmm<0><<<Gg * 4, 256, 0, stream>>>(adjbf, Thi, Tmid, Tlo, dinv_g1, dxw1, b1, h1, nullptr);
    k_tsplit<<<Gg * 16, 256, 0, stream>>>(h1, Thi, Tmid, Tlo);
    k_aggmm<1><<<Gg * 4, 256, 0, stream>>>(adjbf, Thi, Tmid, Tlo, dinv_i1, h1, nullptr, nullptr, s1);
    k_topk<N1, K1><<<Gg, 256, 0, stream>>>(s1, idx1);
    k_gather<K1><<<Gg * K1 / 4, 256, 0, stream>>>(h1, N1, idx1, att1s, att1d, xk1, as1, ad1);
    k_readout<K1><<<Gg, 128, 0, stream>>>(xk1, x1r);
    k_attn<K1, N1><<<Gg * K1 / 4, 256, 0, stream>>>(adj, idx1, as1, ad1, a1, dinv_g2, dinv_i2);

    // stage 2: pooled graph (K1=256), dense attention adjacency a1
    k_gemm_rw<<<Gg * K1 / 64, 256, 0, stream>>>(xk1, W2, xw2, nullptr);
    k_agg<K1, true, 0><<<Gg * (K1 / 64), 256, 0, stream>>>(a1, xw2, dinv_g2, dinv_i2, b2, xw2, h2, nullptr);
    k_agg<K1, false, 1><<<Gg * (K1 / 64), 256, 0, stream>>>(a1, h2, dinv_g2, dinv_i2, b2, h2, nullptr, s2);
    k_topk<K1, K2><<<Gg, 256, 0, stream>>>(s2, idx2);
    k_gather<K2><<<Gg * K2 / 4, 256, 0, stream>>>(h2, K1, idx2, att2s, att2d, xk2, as2, ad2);
    k_readout<K2><<<Gg, 128, 0, stream>>>(xk2, x2r);
    k_attn<K2, K1><<<Gg * K2 / 4, 256, 0, stream>>>(a1, idx2, as2, ad2, a2, dinv_g3, dinv_i3);

    // stage 3: pooled graph (K2=128), dense attention adjacency a2
    k_gemm_rw<<<Gg * K2 / 64, 256, 0, stream>>>(xk2, W3, xw3, nullptr);
    k_agg<K2, true, 0><<<Gg * (K2 / 64), 256, 0, stream>>>(a2, xw3, dinv_g3, dinv_i3, b3, xw3, h3, nullptr);
    k_readout<K2><<<Gg, 128, 0, stream>>>(h3, x3r);

    // final MLP
    k_mlp<<<Gg, 128, 0, stream>>>(x1r, x2r, x3r, Wl1, bl1, Wl2, bl2, Wl3, bl3, out);
}

// Round 4
// 577.232 us; speedup vs baseline: 1.0538x; 1.0538x over previous
//
#include <hip/hip_runtime.h>

// Sizes
#define Gg   128
#define N1   512
#define FH   128
#define K1   256
#define K2   128

typedef __bf16 bf16x8 __attribute__((ext_vector_type(8)));
typedef float  floatx4 __attribute__((ext_vector_type(4)));

__device__ inline float wredsum(float v) {
#pragma unroll
    for (int o = 32; o; o >>= 1) v += __shfl_xor(v, o, 64);
    return v;
}
__device__ inline float wredmax(float v) {
#pragma unroll
    for (int o = 32; o; o >>= 1) v = fmaxf(v, __shfl_xor(v, o, 64));
    return v;
}
__device__ inline unsigned short bf_rne(float x) {
    unsigned u = __float_as_uint(x);
    return (unsigned short)((u + 0x7fffu + ((u >> 16) & 1u)) >> 16);
}
// async global->LDS, 16B per lane; LDS dest wave-uniform base (HW adds lane*16)
__device__ __forceinline__ void gll16(const void* gsrc, void* lds) {
    __builtin_amdgcn_global_load_lds(
        (const __attribute__((address_space(1))) unsigned int*)gsrc,
        (__attribute__((address_space(3))) unsigned int*)lds, 16, 0, 0);
}

// ---------------------------------------------------------------------------
// MERGED: blocks [0,1024) = gemm_rw1 (x @ W1, unscaled); blocks [1024,..) = prep
// (degrees + bf16 adj copy). Independent work co-scheduled: VALU-bound GEMM
// overlaps memory-bound adj sweep. dinv scaling deferred to k_tsplit (bit-exact).
// ---------------------------------------------------------------------------
__global__ __launch_bounds__(256) void k_prep_gemm(const float* __restrict__ adj,
        unsigned short* __restrict__ adjbf,
        float* __restrict__ dinv_gcn, float* __restrict__ dinv_info,
        const float* __restrict__ A, const float* __restrict__ W, float* __restrict__ C) {
    __shared__ float Al[64][68];
    __shared__ float Wl[64][132];
    if (blockIdx.x < Gg * N1 / 64) {
        long long row0 = (long long)blockIdx.x * 64;
        int tid = threadIdx.x, tr = tid >> 4, tc = tid & 15;
        float acc[4][8] = {};
        for (int ch = 0; ch < 2; ++ch) {
            for (int p = tid; p < 1024; p += 256) {
                int r = p >> 4, c4 = p & 15;
                *(float4*)&Al[r][c4 * 4] = *(const float4*)(A + (row0 + r) * 128 + ch * 64 + c4 * 4);
            }
            for (int p = tid; p < 2048; p += 256) {
                int r = p >> 5, c4 = p & 31;
                *(float4*)&Wl[r][c4 * 4] = *(const float4*)(W + (ch * 64 + r) * 128 + c4 * 4);
            }
            __syncthreads();
            for (int k = 0; k < 64; ++k) {
                float4 w0 = *(const float4*)&Wl[k][tc * 8];
                float4 w1 = *(const float4*)&Wl[k][tc * 8 + 4];
                float w[8] = {w0.x, w0.y, w0.z, w0.w, w1.x, w1.y, w1.z, w1.w};
#pragma unroll
                for (int i = 0; i < 4; ++i) {
                    float a = Al[tr * 4 + i][k];
#pragma unroll
                    for (int j = 0; j < 8; ++j) acc[i][j] = fmaf(a, w[j], acc[i][j]);
                }
            }
            __syncthreads();
        }
#pragma unroll
        for (int i = 0; i < 4; ++i) {
            long long r = row0 + tr * 4 + i;
            *(float4*)(C + r * 128 + tc * 8)     = make_float4(acc[i][0], acc[i][1], acc[i][2], acc[i][3]);
            *(float4*)(C + r * 128 + tc * 8 + 4) = make_float4(acc[i][4], acc[i][5], acc[i][6], acc[i][7]);
        }
    } else {
        int wave = threadIdx.x >> 6, lane = threadIdx.x & 63;
        long long row = (long long)(blockIdx.x - Gg * N1 / 64) * 4 + wave;
        const float* ar = adj + row * N1;
        float s = 0.f;
        unsigned short ub[8] __attribute__((aligned(16)));
#pragma unroll
        for (int c = 0; c < 2; ++c) {
            float4 v = *(const float4*)(ar + lane * 8 + c * 4);
            s += (v.x + v.y) + (v.z + v.w);
            ub[c * 4 + 0] = (unsigned short)(__float_as_uint(v.x) >> 16);
            ub[c * 4 + 1] = (unsigned short)(__float_as_uint(v.y) >> 16);
            ub[c * 4 + 2] = (unsigned short)(__float_as_uint(v.z) >> 16);
            ub[c * 4 + 3] = (unsigned short)(__float_as_uint(v.w) >> 16);
        }
        *(uint4*)(adjbf + row * N1 + lane * 8) = *(const uint4*)ub;
        s = wredsum(s);
        if (lane == 0) {
            dinv_gcn[row]  = rsqrtf(s + 1.0f);
            dinv_info[row] = 1.0f / fmaxf(s, 1.0f);
        }
    }
}

// ---------------------------------------------------------------------------
// transpose + 3-way bf16 split: feat[g*512][128] fp32 -> T{hi,mid,lo}
// Optional per-row scale rs (applied before split; same fp32 product as the
// old gemm-epilogue scaling -> bit-exact). k-step-blocked T[g][ks][f][32],
// 16B chunks XOR-swizzled (content chunk c at pos c ^ ((f>>1)&3)).
// ---------------------------------------------------------------------------
__global__ __launch_bounds__(256) void k_tsplit(const float* __restrict__ feat,
        const float* __restrict__ rs,
        unsigned short* __restrict__ Thi, unsigned short* __restrict__ Tmid,
        unsigned short* __restrict__ Tlo) {
    __shared__ float tile[64 * 65];
    int b = blockIdx.x;                    // G * 8 * 2
    int g = b >> 4, rb = (b >> 1) & 7, cb = b & 1;
    int t = threadIdx.x;
    {
        int r0 = t >> 4, c4 = t & 15;
#pragma unroll
        for (int i = 0; i < 4; ++i) {
            int r = r0 + i * 16;
            float4 v = *(const float4*)(feat + ((long long)g * 512 + rb * 64 + r) * 128 + cb * 64 + c4 * 4);
            if (rs) {
                float sc = rs[(long long)g * 512 + rb * 64 + r];
                v.x *= sc; v.y *= sc; v.z *= sc; v.w *= sc;
            }
            tile[r * 65 + c4 * 4 + 0] = v.x;
            tile[r * 65 + c4 * 4 + 1] = v.y;
            tile[r * 65 + c4 * 4 + 2] = v.z;
            tile[r * 65 + c4 * 4 + 3] = v.w;
        }
    }
    __syncthreads();
    int tf = t >> 2, chunk = t & 3;
    unsigned short hbuf[16] __attribute__((aligned(16)));
    unsigned short mbuf[16] __attribute__((aligned(16)));
    unsigned short lbuf[16] __attribute__((aligned(16)));
#pragma unroll
    for (int i = 0; i < 16; ++i) {
        int m = chunk * 16 + i;
        float v = tile[m * 65 + tf];
        unsigned short h = bf_rne(v);
        float fh = __uint_as_float((unsigned)h << 16);
        float r1 = v - fh;
        unsigned short md = bf_rne(r1);
        float fm = __uint_as_float((unsigned)md << 16);
        float r2 = r1 - fm;
        unsigned short lo = bf_rne(r2);
        hbuf[i] = h; mbuf[i] = md; lbuf[i] = lo;
    }
    int sxz = (tf >> 1) & 3;
    int c0 = (chunk & 1) * 2;
    int p0 = (c0 ^ sxz) * 8, p1 = ((c0 + 1) ^ sxz) * 8;
    long long obase = (long long)g * 65536 + (rb * 2 + (chunk >> 1)) * 4096
                    + (cb * 64 + tf) * 32;
    *(uint4*)(Thi + obase + p0)  = *(const uint4*)&hbuf[0];
    *(uint4*)(Thi + obase + p1)  = *(const uint4*)&hbuf[8];
    *(uint4*)(Tmid + obase + p0) = *(const uint4*)&mbuf[0];
    *(uint4*)(Tmid + obase + p1) = *(const uint4*)&mbuf[8];
    *(uint4*)(Tlo + obase + p0)  = *(const uint4*)&lbuf[0];
    *(uint4*)(Tlo + obase + p1)  = *(const uint4*)&lbuf[8];
}

// ---------------------------------------------------------------------------
// MFMA aggregation: C = adj(512x512, exact bf16) @ (Bhi+Bmid+Blo)(512x128)
//  EPI 0 (gcn):  outH[m][n] = relu(di*(C + di*hx) + bias)  (hx = UNscaled xw)
//  EPI 1 (info): outS[m]    = sum_n |hx - C*di|
// 2-phase pipeline, DMA-staged A/B, XOR chunk-swizzle.
// ---------------------------------------------------------------------------
template<int EPI>
__global__ __launch_bounds__(256) void k_aggmm(const unsigned short* __restrict__ adjbf,
        const unsigned short* __restrict__ Bhi, const unsigned short* __restrict__ Bmid,
        const unsigned short* __restrict__ Blo,
        const float* __restrict__ dvec, const float* __restrict__ hx,
        const float* __restrict__ bias, float* __restrict__ outH, float* __restrict__ outS) {
    __shared__ unsigned short Al[2][4096];
    __shared__ unsigned short Blin[2][3][4096];
    __shared__ float sred[2][128];
    int b = blockIdx.x;                               // 512 blocks
    int g  = (b & 7) + ((b >> 5) << 3);               // XCD swizzle
    int rb = (b >> 3) & 3;
    int tid = threadIdx.x;
    int w = tid >> 6, lane = tid & 63;
    int wm = w >> 1, wn = w & 1;
    int ln = lane & 15, quad = lane >> 4;
    int aoff = ((quad ^ ((lane >> 1) & 3)) << 4);
    floatx4 acc[4][4];
#pragma unroll
    for (int i = 0; i < 4; ++i)
#pragma unroll
        for (int j = 0; j < 4; ++j) { floatx4 z = {0.f, 0.f, 0.f, 0.f}; acc[i][j] = z; }

    const char* bsrc0 = (const char*)(Bhi  + (long long)g * 65536);
    const char* bsrc1 = (const char*)(Bmid + (long long)g * 65536);
    const char* bsrc2 = (const char*)(Blo  + (long long)g * 65536);
    int r1 = w * 32 + (lane >> 2);
    int c1 = (lane & 3) ^ ((r1 >> 1) & 3);
    int r2 = r1 + 16;
    int c2 = (lane & 3) ^ ((r2 >> 1) & 3);
    const unsigned short* abase = adjbf + ((long long)g * 512 + rb * 128) * 512;
    const unsigned short* asrc1 = abase + (long long)r1 * 512 + c1 * 8;
    const unsigned short* asrc2 = abase + (long long)r2 * 512 + c2 * 8;

#define STAGE(bi, kkv) do {                                                   \
        char* aldst = (char*)&Al[bi][0] + w * 2048;                           \
        gll16(asrc1 + (kkv), aldst);                                          \
        gll16(asrc2 + (kkv), aldst + 1024);                                   \
        long long soff = (long long)((kkv) >> 5) * 8192 + (w * 2048) + (lane << 4); \
        char* l0 = (char*)&Blin[bi][0][0] + w * 2048;                         \
        char* l1 = (char*)&Blin[bi][1][0] + w * 2048;                         \
        char* l2 = (char*)&Blin[bi][2][0] + w * 2048;                         \
        gll16(bsrc0 + soff,        l0);                                       \
        gll16(bsrc0 + soff + 1024, l0 + 1024);                                \
        gll16(bsrc1 + soff,        l1);                                       \
        gll16(bsrc1 + soff + 1024, l1 + 1024);                                \
        gll16(bsrc2 + soff,        l2);                                       \
        gll16(bsrc2 + soff + 1024, l2 + 1024);                                \
    } while (0)

    STAGE(0, 0);
    for (int kk = 0; kk < 512; kk += 32) {
        int cur = (kk >> 5) & 1;
        if (kk + 32 < 512) {
            STAGE(cur ^ 1, kk + 32);
            asm volatile("s_waitcnt vmcnt(8)" ::: "memory");
        } else {
            asm volatile("s_waitcnt vmcnt(0)" ::: "memory");
        }
        __builtin_amdgcn_sched_barrier(0);
        __builtin_amdgcn_s_barrier();
        bf16x8 af[4];
#pragma unroll
        for (int tm = 0; tm < 4; ++tm)
            af[tm] = *(const bf16x8*)((const char*)&Al[cur][0] + (wm * 64 + tm * 16 + ln) * 64 + aoff);
#pragma unroll
        for (int s = 0; s < 3; ++s) {
#pragma unroll
            for (int tn = 0; tn < 4; ++tn) {
                bf16x8 bfr = *(const bf16x8*)((const char*)&Blin[cur][s][0]
                                              + (wn * 64 + tn * 16 + ln) * 64 + aoff);
#pragma unroll
                for (int tm = 0; tm < 4; ++tm)
                    acc[tm][tn] = __builtin_amdgcn_mfma_f32_16x16x32_bf16(af[tm], bfr, acc[tm][tn], 0, 0, 0);
            }
        }
        __builtin_amdgcn_sched_barrier(0);
        __builtin_amdgcn_s_barrier();
    }
#undef STAGE
    long long rowbase = (long long)g * 512 + rb * 128;
    if (EPI == 0) {
#pragma unroll
        for (int tm = 0; tm < 4; ++tm)
#pragma unroll
        for (int r = 0; r < 4; ++r) {
            int ml = wm * 64 + tm * 16 + quad * 4 + r;
            long long grow = rowbase + ml;
            float di = dvec[grow];
#pragma unroll
            for (int tn = 0; tn < 4; ++tn) {
                int nc = wn * 64 + tn * 16 + ln;
                float hv = hx[grow * 128 + nc];
                float o = fmaxf(fmaf(di, acc[tm][tn][r] + di * hv, bias[nc]), 0.f);
                outH[grow * 128 + nc] = o;
            }
        }
    } else {
#pragma unroll
        for (int tm = 0; tm < 4; ++tm)
#pragma unroll
        for (int r = 0; r < 4; ++r) {
            int ml = wm * 64 + tm * 16 + quad * 4 + r;
            long long grow = rowbase + ml;
            float di = dvec[grow];
            float v = 0.f;
#pragma unroll
            for (int tn = 0; tn < 4; ++tn) {
                int nc = wn * 64 + tn * 16 + ln;
                float hv = hx[grow * 128 + nc];
                v += fabsf(hv - acc[tm][tn][r] * di);
            }
            v += __shfl_xor(v, 1); v += __shfl_xor(v, 2);
            v += __shfl_xor(v, 4); v += __shfl_xor(v, 8);
            if (ln == 0) sred[wn][ml] = v;
        }
        __syncthreads();
        if (tid < 128) outS[rowbase + tid] = sred[0][tid] + sred[1][tid];
    }
}

// ---------------------------------------------------------------------------
// Row-weight GEMM: C[M,128] = rs[row] * (A[M,128] @ W[128,128])  (rs optional)
// ---------------------------------------------------------------------------
__global__ __launch_bounds__(256) void k_gemm_rw(const float* __restrict__ A,
        const float* __restrict__ W, float* __restrict__ C,
        const float* __restrict__ rs) {
    __shared__ float Al[64][68];
    __shared__ float Wl[64][132];
    long long row0 = (long long)blockIdx.x * 64;
    int tid = threadIdx.x, tr = tid >> 4, tc = tid & 15;
    float acc[4][8] = {};
    for (int ch = 0; ch < 2; ++ch) {
        for (int p = tid; p < 1024; p += 256) {
            int r = p >> 4, c4 = p & 15;
            *(float4*)&Al[r][c4 * 4] = *(const float4*)(A + (row0 + r) * 128 + ch * 64 + c4 * 4);
        }
        for (int p = tid; p < 2048; p += 256) {
            int r = p >> 5, c4 = p & 31;
            *(float4*)&Wl[r][c4 * 4] = *(const float4*)(W + (ch * 64 + r) * 128 + c4 * 4);
        }
        __syncthreads();
        for (int k = 0; k < 64; ++k) {
            float4 w0 = *(const float4*)&Wl[k][tc * 8];
            float4 w1 = *(const float4*)&Wl[k][tc * 8 + 4];
            float w[8] = {w0.x, w0.y, w0.z, w0.w, w1.x, w1.y, w1.z, w1.w};
#pragma unroll
            for (int i = 0; i < 4; ++i) {
                float a = Al[tr * 4 + i][k];
#pragma unroll
                for (int j = 0; j < 8; ++j) acc[i][j] = fmaf(a, w[j], acc[i][j]);
            }
        }
        __syncthreads();
    }
#pragma unroll
    for (int i = 0; i < 4; ++i) {
        long long r = row0 + tr * 4 + i;
        float sc = rs ? rs[r] : 1.0f;
        *(float4*)(C + r * 128 + tc * 8)     = make_float4(sc * acc[i][0], sc * acc[i][1], sc * acc[i][2], sc * acc[i][3]);
        *(float4*)(C + r * 128 + tc * 8 + 4) = make_float4(sc * acc[i][4], sc * acc[i][5], sc * acc[i][6], sc * acc[i][7]);
    }
}

// ---------------------------------------------------------------------------
// top-k: bitonic sort of packed keys (~ord(val) << 32 | idx) ascending
// ---------------------------------------------------------------------------
template<int NT, int KSEL>
__global__ __launch_bounds__(256) void k_topk(const float* __restrict__ s, int* __restrict__ idx) {
    __shared__ unsigned long long keys[NT];
    int g = blockIdx.x;
    const float* sg = s + g * NT;
    for (int t = threadIdx.x; t < NT; t += 256) {
        unsigned int b = __float_as_uint(sg[t]);
        unsigned int ord = (b & 0x80000000u) ? ~b : (b | 0x80000000u);
        keys[t] = ((unsigned long long)(~ord) << 32) | (unsigned int)t;
    }
    __syncthreads();
    for (int k = 2; k <= NT; k <<= 1) {
        for (int j = k >> 1; j > 0; j >>= 1) {
            for (int i = threadIdx.x; i < NT; i += 256) {
                int l = i ^ j;
                if (l > i) {
                    bool dir = ((i & k) == 0);
                    unsigned long long a = keys[i], b2 = keys[l];
                    bool sw = dir ? (a > b2) : (a < b2);
                    if (sw) { keys[i] = b2; keys[l] = a; }
                }
            }
            __syncthreads();
        }
    }
    for (int t = threadIdx.x; t < KSEL; t += 256)
        idx[g * KSEL + t] = (int)(keys[t] & 0xffffffffu);
}

// ---------------------------------------------------------------------------
// gather pooled rows + attention dot products
// ---------------------------------------------------------------------------
template<int KK>
__global__ __launch_bounds__(256) void k_gather(const float* __restrict__ h, int srcN,
        const int* __restrict__ idx, const float* __restrict__ atts, const float* __restrict__ attd,
        float* __restrict__ xk, float* __restrict__ as_, float* __restrict__ ad_) {
    int wave = threadIdx.x >> 6, lane = threadIdx.x & 63;
    int r = blockIdx.x * 4 + wave;          // < G*KK
    int g = r / KK;
    int j = idx[r];
    float2 v = *(const float2*)(h + ((long long)g * srcN + j) * 128 + lane * 2);
    *(float2*)(xk + (long long)r * 128 + lane * 2) = v;
    float2 sv = *(const float2*)(atts + lane * 2);
    float2 dv = *(const float2*)(attd + lane * 2);
    float ps = v.x * sv.x + v.y * sv.y;
    float pd = v.x * dv.x + v.y * dv.y;
    ps = wredsum(ps); pd = wredsum(pd);
    if (lane == 0) { as_[r] = ps; ad_[r] = pd; }
}

// ---------------------------------------------------------------------------
// MERGED attention + readout.
// blocks [0, G*KK/4): attn = softmax(leaky(as_i+ad_j) + adjSrc[idx_i,idx_j]) + deg
//   (adjSrc is bf16 when BF16, exact for 0/1 adjacency)
// blocks [G*KK/4, +G): readout of xk -> xo[G,256] (max | mean)
// ---------------------------------------------------------------------------
template<int KK, int SRCN, bool BF16>
__global__ __launch_bounds__(256) void k_attnro(const void* __restrict__ adjSrc,
        const int* __restrict__ idx, const float* __restrict__ as_, const float* __restrict__ ad_,
        float* __restrict__ attn, float* __restrict__ dgo, float* __restrict__ dio,
        const float* __restrict__ xk, float* __restrict__ xo) {
    constexpr int E = KK / 64;
    constexpr int nAttn = Gg * KK / 4;
    __shared__ int   idxL[KK];
    __shared__ float adL[KK];
    __shared__ float rowL[4][SRCN];
    if ((int)blockIdx.x >= nAttn) {
        int g = blockIdx.x - nAttn, t = threadIdx.x;
        if (t < 128) {
            const float* p = xk + (long long)g * KK * 128 + t;
            float m = -1e30f, s = 0.f;
            for (int r = 0; r < KK; ++r) { float v = p[r * 128]; m = fmaxf(m, v); s += v; }
            xo[g * 256 + t] = m;
            xo[g * 256 + 128 + t] = s * (1.0f / KK);
        }
        return;
    }
    int bpg = KK / 4;
    int g = blockIdx.x / bpg;
    int wave = threadIdx.x >> 6, lane = threadIdx.x & 63;
    int i = (blockIdx.x % bpg) * 4 + wave;
    for (int t = threadIdx.x; t < KK; t += 256) { idxL[t] = idx[g * KK + t]; adL[t] = ad_[g * KK + t]; }
    __syncthreads();
    int ri = idxL[i];
    if (BF16) {
        const unsigned short* arow = (const unsigned short*)adjSrc + ((long long)g * SRCN + ri) * SRCN;
        for (int c = lane; c < SRCN; c += 64)
            rowL[wave][c] = __uint_as_float((unsigned)arow[c] << 16);
    } else {
        const float* arow = (const float*)adjSrc + ((long long)g * SRCN + ri) * SRCN;
        for (int c = lane; c < SRCN; c += 64) rowL[wave][c] = arow[c];
    }
    float asi = as_[g * KK + i];
    float vals[E];
    float m = -1e30f;
#pragma unroll
    for (int e = 0; e < E; ++e) {
        int j = e * 64 + lane;
        float x = asi + adL[j];
        x = (x >= 0.f) ? x : 0.2f * x;
        x += rowL[wave][idxL[j]];       // LAMB = 1.0
        vals[e] = x; m = fmaxf(m, x);
    }
    m = wredmax(m);
    float S = 0.f;
#pragma unroll
    for (int e = 0; e < E; ++e) { vals[e] = expf(vals[e] - m); S += vals[e]; }
    S = wredsum(S);
    float inv = 1.f / S, rs = 0.f;
    float* orow = attn + ((long long)g * KK + i) * KK;
#pragma unroll
    for (int e = 0; e < E; ++e) { float p = vals[e] * inv; rs += p; orow[e * 64 + lane] = p; }
    rs = wredsum(rs);
    if (lane == 0) { dgo[g * KK + i] = rsqrtf(rs + 1.f); dio[g * KK + i] = 1.f / fmaxf(rs, 1.f); }
}

// ---------------------------------------------------------------------------
// dense batched agg GEMM: C = A(KKxKK) @ [opt dinv_j *] Y(KKx128)
//  EPI 0: outH = relu(di*C + di^2*hx + bias)   EPI 1: outS_i = sum_f |hx - C*di|
// ---------------------------------------------------------------------------
template<int KK, bool SCALEY, int EPI>
__global__ __launch_bounds__(256) void k_agg(const float* __restrict__ A, const float* __restrict__ Y,
        const float* __restrict__ dg, const float* __restrict__ di_,
        const float* __restrict__ bias, const float* __restrict__ hx,
        float* __restrict__ outH, float* __restrict__ outS) {
    __shared__ float Al[64][68];
    __shared__ float Yl[64][132];
    __shared__ float red[64][17];
    constexpr int RB = KK / 64;
    int g = blockIdx.x / RB;
    int rb = blockIdx.x % RB;
    const float* Ag = A + (long long)g * KK * KK;
    const float* Yg = Y + (long long)g * KK * 128;
    int tid = threadIdx.x, tr = tid >> 4, tc = tid & 15;
    float acc[4][8] = {};
    for (int ch = 0; ch < KK / 64; ++ch) {
        for (int p = tid; p < 1024; p += 256) {
            int r = p >> 4, c4 = p & 15;
            *(float4*)&Al[r][c4 * 4] = *(const float4*)(Ag + (rb * 64 + r) * KK + ch * 64 + c4 * 4);
        }
        for (int p = tid; p < 2048; p += 256) {
            int r = p >> 5, c4 = p & 31;
            float4 v = *(const float4*)(Yg + (ch * 64 + r) * 128 + c4 * 4);
            if (SCALEY) { float sc = dg[g * KK + ch * 64 + r]; v.x *= sc; v.y *= sc; v.z *= sc; v.w *= sc; }
            *(float4*)&Yl[r][c4 * 4] = v;
        }
        __syncthreads();
        for (int k = 0; k < 64; ++k) {
            float4 w0 = *(const float4*)&Yl[k][tc * 8];
            float4 w1 = *(const float4*)&Yl[k][tc * 8 + 4];
            float w[8] = {w0.x, w0.y, w0.z, w0.w, w1.x, w1.y, w1.z, w1.w};
#pragma unroll
            for (int i = 0; i < 4; ++i) {
                float a = Al[tr * 4 + i][k];
#pragma unroll
                for (int j = 0; j < 8; ++j) acc[i][j] = fmaf(a, w[j], acc[i][j]);
            }
        }
        __syncthreads();
    }
    int i0 = rb * 64 + tr * 4;
    if (EPI == 0) {
#pragma unroll
        for (int i = 0; i < 4; ++i) {
            long long gi = (long long)g * KK + i0 + i;
            float d = dg[gi], dd = d * d;
            float4 x0 = *(const float4*)(hx + gi * 128 + tc * 8);
            float4 x1 = *(const float4*)(hx + gi * 128 + tc * 8 + 4);
            float4 b0 = *(const float4*)(bias + tc * 8);
            float4 b1 = *(const float4*)(bias + tc * 8 + 4);
            float4 o0, o1;
            o0.x = fmaxf(fmaf(d, acc[i][0], fmaf(dd, x0.x, b0.x)), 0.f);
            o0.y = fmaxf(fmaf(d, acc[i][1], fmaf(dd, x0.y, b0.y)), 0.f);
            o0.z = fmaxf(fmaf(d, acc[i][2], fmaf(dd, x0.z, b0.z)), 0.f);
            o0.w = fmaxf(fmaf(d, acc[i][3], fmaf(dd, x0.w, b0.w)), 0.f);
            o1.x = fmaxf(fmaf(d, acc[i][4], fmaf(dd, x1.x, b1.x)), 0.f);
            o1.y = fmaxf(fmaf(d, acc[i][5], fmaf(dd, x1.y, b1.y)), 0.f);
            o1.z = fmaxf(fmaf(d, acc[i][6], fmaf(dd, x1.z, b1.z)), 0.f);
            o1.w = fmaxf(fmaf(d, acc[i][7], fmaf(dd, x1.w, b1.w)), 0.f);
            *(float4*)(outH + gi * 128 + tc * 8)     = o0;
            *(float4*)(outH + gi * 128 + tc * 8 + 4) = o1;
        }
    } else {
#pragma unroll
        for (int i = 0; i < 4; ++i) {
            long long gi = (long long)g * KK + i0 + i;
            float d = di_[gi];
            float4 x0 = *(const float4*)(hx + gi * 128 + tc * 8);
            float4 x1 = *(const float4*)(hx + gi * 128 + tc * 8 + 4);
            float p = fabsf(x0.x - acc[i][0] * d) + fabsf(x0.y - acc[i][1] * d)
                    + fabsf(x0.z - acc[i][2] * d) + fabsf(x0.w - acc[i][3] * d)
                    + fabsf(x1.x - acc[i][4] * d) + fabsf(x1.y - acc[i][5] * d)
                    + fabsf(x1.z - acc[i][6] * d) + fabsf(x1.w - acc[i][7] * d);
            red[tr * 4 + i][tc] = p;
        }
        __syncthreads();
        if (tid < 64) {
            float s = 0.f;
#pragma unroll
            for (int t = 0; t < 16; ++t) s += red[tid][t];
            outS[(long long)g * KK + rb * 64 + tid] = s;
        }
    }
}

// ---------------------------------------------------------------------------
// final MLP + softmax, one block per graph; readout of h3 fused inline
// ---------------------------------------------------------------------------
__global__ __launch_bounds__(128) void k_mlp(const float* __restrict__ x1, const float* __restrict__ x2,
        const float* __restrict__ h3,
        const float* __restrict__ Wl1, const float* __restrict__ bl1,
        const float* __restrict__ Wl2, const float* __restrict__ bl2,
        const float* __restrict__ Wl3, const float* __restrict__ bl3,
        float* __restrict__ out) {
    __shared__ float z[256], z1[128], z2[64], lg[10];
    int g = blockIdx.x, t = threadIdx.x;
    {   // inline readout of h3 (K2=128 rows)
        const float* p = h3 + (long long)g * K2 * 128 + t;
        float m = -1e30f, s = 0.f;
        for (int r = 0; r < K2; ++r) { float v = p[r * 128]; m = fmaxf(m, v); s += v; }
        float x3a = m, x3b = s * (1.0f / K2);
        z[t]       = fmaxf(x1[g * 256 + t], 0.f)       + fmaxf(x2[g * 256 + t], 0.f)       + fmaxf(x3a, 0.f);
        z[t + 128] = fmaxf(x1[g * 256 + 128 + t], 0.f) + fmaxf(x2[g * 256 + 128 + t], 0.f) + fmaxf(x3b, 0.f);
    }
    __syncthreads();
    {
        float acc = bl1[t];
        for (int k = 0; k < 256; ++k) acc = fmaf(z[k], Wl1[k * 128 + t], acc);
        z1[t] = fmaxf(acc, 0.f);
    }
    __syncthreads();
    if (t < 64) {
        float acc = bl2[t];
        for (int k = 0; k < 128; ++k) acc = fmaf(z1[k], Wl2[k * 64 + t], acc);
        z2[t] = fmaxf(acc, 0.f);
    }
    __syncthreads();
    if (t < 10) {
        float acc = bl3[t];
        for (int k = 0; k < 64; ++k) acc = fmaf(z2[k], Wl3[k * 10 + t], acc);
        lg[t] = acc;
    }
    __syncthreads();
    if (t == 0) {
        float m = -1e30f;
        for (int c = 0; c < 10; ++c) m = fmaxf(m, lg[c]);
        float S = 0.f;
        float e[10];
        for (int c = 0; c < 10; ++c) { e[c] = expf(lg[c] - m); S += e[c]; }
        float inv = 1.f / S;
        for (int c = 0; c < 10; ++c) out[g * 10 + c] = e[c] * inv;
    }
}

// ---------------------------------------------------------------------------
extern "C" void kernel_launch(void* const* d_in, const int* in_sizes, int n_in,
                              void* d_out, int out_size, void* d_ws, size_t ws_size,
                              hipStream_t stream) {
    const float* x     = (const float*)d_in[0];
    const float* adj   = (const float*)d_in[1];
    const float* W1    = (const float*)d_in[2];
    const float* b1    = (const float*)d_in[3];
    const float* W2    = (const float*)d_in[4];
    const float* b2    = (const float*)d_in[5];
    const float* W3    = (const float*)d_in[6];
    const float* b3    = (const float*)d_in[7];
    const float* att1s = (const float*)d_in[8];
    const float* att1d = (const float*)d_in[9];
    const float* att2s = (const float*)d_in[10];
    const float* att2d = (const float*)d_in[11];
    const float* Wl1   = (const float*)d_in[12];
    const float* bl1   = (const float*)d_in[13];
    const float* Wl2   = (const float*)d_in[14];
    const float* bl2   = (const float*)d_in[15];
    const float* Wl3   = (const float*)d_in[16];
    const float* bl3   = (const float*)d_in[17];
    float* out = (float*)d_out;

    char* ws = (char*)d_ws;
    // --- workspace layout (lifetimes annotated; harness ws >= 512MB) ---
    unsigned short* Thi  = (unsigned short*)(ws + 0);
    unsigned short* Tmid = (unsigned short*)(ws + 16777216);
    unsigned short* Tlo  = (unsigned short*)(ws + 33554432);
    float* xk1 = (float*)(ws + 0);            // after info1 done
    float* xw2 = (float*)(ws + 16777216);
    float* h2  = (float*)(ws + 33554432);
    float* xk2 = (float*)(ws + 16777216);     // xw2 slot (dead after agg2-epi0)
    float* a2  = (float*)(ws + 25165824);
    float* xw3 = (float*)(ws + 0);            // xk1 slot (dead after readout1)
    float* h3  = (float*)(ws + 8388608);
    float* dxw1 = (float*)(ws + 50331648);    // xw (UNscaled) -> h1 -> a1
    float* h1   = dxw1;
    float* a1   = dxw1;
    float* s1      = (float*)(ws + 83886080);
    int*   idx1    = (int*)  (ws + 84148224);
    float* as1     = (float*)(ws + 84279296);
    float* ad1     = (float*)(ws + 84410368);
    float* dinv_g1 = (float*)(ws + 84541440);
    float* dinv_i1 = (float*)(ws + 84803584);
    float* dinv_g2 = (float*)(ws + 85065728);
    float* dinv_i2 = (float*)(ws + 85196800);
    float* x1r     = (float*)(ws + 85327872);
    float* s2      = (float*)(ws + 85458944);
    int*   idx2    = (int*)  (ws + 85590016);
    float* as2     = (float*)(ws + 85655552);
    float* ad2     = (float*)(ws + 85721088);
    float* dinv_g3 = (float*)(ws + 85786624);
    float* dinv_i3 = (float*)(ws + 85852160);
    float* x2r     = (float*)(ws + 85917696);
    unsigned short* adjbf = (unsigned short*)(ws + 100663296);  // [96MB..160MB)

    // stage 1: merged prep+gemm1, then bf16-split MFMA aggregations
    k_prep_gemm<<<Gg * N1 / 64 + Gg * N1 / 4, 256, 0, stream>>>(adj, adjbf, dinv_g1, dinv_i1, x, W1, dxw1);
    k_tsplit<<<Gg * 16, 256, 0, stream>>>(dxw1, dinv_g1, Thi, Tmid, Tlo);
    k_aggmm<0><<<Gg * 4, 256, 0, stream>>>(adjbf, Thi, Tmid, Tlo, dinv_g1, dxw1, b1, h1, nullptr);
    k_tsplit<<<Gg * 16, 256, 0, stream>>>(h1, nullptr, Thi, Tmid, Tlo);
    k_aggmm<1><<<Gg * 4, 256, 0, stream>>>(adjbf, Thi, Tmid, Tlo, dinv_i1, h1, nullptr, nullptr, s1);
    k_topk<N1, K1><<<Gg, 256, 0, stream>>>(s1, idx1);
    k_gather<K1><<<Gg * K1 / 4, 256, 0, stream>>>(h1, N1, idx1, att1s, att1d, xk1, as1, ad1);
    k_attnro<K1, N1, true><<<Gg * K1 / 4 + Gg, 256, 0, stream>>>(adjbf, idx1, as1, ad1, a1, dinv_g2, dinv_i2, xk1, x1r);

    // stage 2: pooled graph (K1=256), dense attention adjacency a1
    k_gemm_rw<<<Gg * K1 / 64, 256, 0, stream>>>(xk1, W2, xw2, nullptr);
    k_agg<K1, true, 0><<<Gg * (K1 / 64), 256, 0, stream>>>(a1, xw2, dinv_g2, dinv_i2, b2, xw2, h2, nullptr);
    k_agg<K1, false, 1><<<Gg * (K1 / 64), 256, 0, stream>>>(a1, h2, dinv_g2, dinv_i2, b2, h2, nullptr, s2);
    k_topk<K1, K2><<<Gg, 256, 0, stream>>>(s2, idx2);
    k_gather<K2><<<Gg * K2 / 4, 256, 0, stream>>>(h2, K1, idx2, att2s, att2d, xk2, as2, ad2);
    k_attnro<K2, K1, false><<<Gg * K2 / 4 + Gg, 256, 0, stream>>>(a1, idx2, as2, ad2, a2, dinv_g3, dinv_i3, xk2, x2r);

    // stage 3: pooled graph (K2=128), dense attention adjacency a2
    k_gemm_rw<<<Gg * K2 / 64, 256, 0, stream>>>(xk2, W3, xw3, nullptr);
    k_agg<K2, true, 0><<<Gg * (K2 / 64), 256, 0, stream>>>(a2, xw3, dinv_g3, dinv_i3, b3, xw3, h3, nullptr);

    // final MLP (+ inline readout of h3)
    k_mlp<<<Gg, 128, 0, stream>>>(x1r, x2r, h3, Wl1, bl1, Wl2, bl2, Wl3, bl3, out);
}